// Round 4
// baseline (723.924 us; speedup 1.0000x reference)
//
#include <hip/hip_runtime.h>

typedef unsigned short u16;
typedef __attribute__((ext_vector_type(8))) short short8;
typedef __attribute__((ext_vector_type(4))) float f32x4;

#define B_   2
#define N_   5
#define K_   5
#define Q_   4
#define T_   5
#define D_   768
#define L_   128
#define BN_  (B_*N_)            // 10
#define BNK_ (B_*N_*K_)         // 50
#define BQ_  (B_*N_*Q_*N_)      // 200
#define K4_  (4*D_)             // 3072
#define AST  40                 // LDS row stride in shorts (32 + 8 pad)

#define QEMB_N  (40*128*768)    // 3,932,160
#define PROJW_N (768*3072)      // 2,359,296

__device__ __forceinline__ float bf2f(u16 u) {
    return __uint_as_float(((unsigned)u) << 16);
}
__device__ __forceinline__ u16 f2bf(float f) {
    unsigned u = __float_as_uint(f);
    return (u16)((u + 0x7fffu + ((u >> 16) & 1u)) >> 16);
}
// dual-dtype scalar load (inputs are f32 in this harness; bf16 path kept for safety)
__device__ __forceinline__ float ldf(const void* p, long i, bool isf32) {
    return isf32 ? ((const float*)p)[i] : bf2f(((const u16*)p)[i]);
}

// fuse: c=0 -> m1, 1 -> m2, 2 -> |m1-m2|, 3 -> m1*m2
__device__ __forceinline__ short8 fuse8(int c, short8 a, short8 b) {
    if (c == 0) return a;
    if (c == 1) return b;
    short8 o;
    #pragma unroll
    for (int i = 0; i < 8; ++i) {
        float x = bf2f((u16)a[i]), y = bf2f((u16)b[i]);
        float r = (c == 2) ? fabsf(x - y) : x * y;
        o[i] = (short)f2bf(r);
    }
    return o;
}

// ---------------- K0: canonicalize input tensor to bf16 (runtime dtype detect) ----------------
__global__ void k_convert(const void* __restrict__ src, u16* __restrict__ dst, int n,
                          const u16* __restrict__ detect) {
    bool isf32 = (detect[0] != 0x3F80u);   // support_mask[0] == 1.0 always
    int i = blockIdx.x * 256 + threadIdx.x;
    int stride = gridDim.x * 256;
    if (isf32) {
        const float* s = (const float*)src;
        for (; i < n; i += stride) dst[i] = f2bf(s[i]);
    } else {
        const u16* s = (const u16*)src;
        for (; i < n; i += stride) dst[i] = s[i];
    }
}

// ---------------- K1: per-shot tag prototypes (dual-dtype direct reads) ----------------
__global__ void k_proto_shot(const void* __restrict__ label, const void* __restrict__ smask,
                             const void* __restrict__ semb, float* __restrict__ proto_shot) {
    bool isf32 = (((const u16*)smask)[0] != 0x3F80u);
    int bnk = blockIdx.x;
    __shared__ int   s_tag[L_];
    __shared__ float s_w[L_];
    __shared__ float s_cnt[T_];
    int tid = threadIdx.x;
    if (tid < L_) {
        long base = ((long)bnk * L_ + tid) * T_;
        float best = ldf(label, base, isf32); int bi = 0;
        #pragma unroll
        for (int t = 1; t < T_; ++t) {
            float v = ldf(label, base + t, isf32);
            if (v > best) { best = v; bi = t; }
        }
        s_tag[tid] = bi;
        s_w[tid]   = (bi == 0) ? ldf(smask, (long)bnk * L_ + tid, isf32) : 1.0f;
    }
    __syncthreads();
    if (tid < T_) {
        float c = 0.f;
        for (int l = 0; l < L_; ++l) if (s_tag[l] == tid) c += s_w[l];
        s_cnt[tid] = c;
    }
    __syncthreads();
    float acc[3][T_] = {};
    for (int l = 0; l < L_; ++l) {
        float w = s_w[l]; int tg = s_tag[l];
        long ebase = ((long)bnk * L_ + l) * D_;
        #pragma unroll
        for (int s = 0; s < 3; ++s) {
            float e = ldf(semb, ebase + tid + s * 256, isf32) * w;
            #pragma unroll
            for (int t = 0; t < T_; ++t) acc[s][t] += (tg == t) ? e : 0.0f;
        }
    }
    #pragma unroll
    for (int s = 0; s < 3; ++s) {
        int d = tid + s * 256;
        #pragma unroll
        for (int t = 0; t < T_; ++t) {
            float c = s_cnt[t];
            float v = (c > 0.f) ? acc[s][t] / fmaxf(c, 1.f) : 0.f;
            proto_shot[(bnk * T_ + t) * D_ + d] = v;
        }
    }
}

// ---------------- K1b: mean over K shots ----------------
__global__ void k_proto_mean(const float* __restrict__ proto_shot,
                             float* __restrict__ proto_f32, u16* __restrict__ proto_bf) {
    int idx = blockIdx.x * 256 + threadIdx.x;              // < 10*5*768 = 38400
    if (idx >= BN_ * T_ * D_) return;
    int bn = idx / (T_ * D_);
    int rem = idx - bn * (T_ * D_);
    float s = 0.f;
    #pragma unroll
    for (int k = 0; k < K_; ++k) s += proto_shot[(bn * K_ + k) * (T_ * D_) + rem];
    s *= (1.f / K_);
    proto_f32[idx] = s;
    proto_bf[idx]  = f2bf(s);
}

// ---------------- K2: co-attention (full f32 inputs) -> support_ (bf16), p2m weights ----------------
__global__ void k_attn(const void* __restrict__ qemb_raw, const void* __restrict__ qmask_raw,
                       const float* __restrict__ proto_f32,
                       u16* __restrict__ sup_ws, float* __restrict__ p2m_ws,
                       float* __restrict__ qssum_ws) {
    bool isf32 = (((const u16*)qmask_raw)[0] != 0x3F80u) || true; // qmask may be 0; decide via first elem of... keep dual
    // robust detect: qmask entries are 0.0 or 1.0; as bf16 the value 1.0 is 0x3F80 and 0.0 is 0x0000.
    // If dtype were bf16, float-interp of first two u16 would be tiny/denormal. Use size-independent probe:
    // (we know from round-3 evidence inputs are f32; the '|| true' pins f32 but keeps the ldf structure)
    int bq = blockIdx.x;
    int q_idx = bq / N_;
    int bn = (bq / (N_ * Q_ * N_)) * N_ + (bq % N_);
    __shared__ float s_proto[T_ * D_];
    __shared__ float s_att[T_][L_];
    __shared__ float s_ps[T_][L_];
    __shared__ float s_qm[L_];
    int tid = threadIdx.x;
    for (int i = tid; i < T_ * D_; i += 256) s_proto[i] = proto_f32[bn * T_ * D_ + i];
    if (tid < L_) s_qm[tid] = ldf(qmask_raw, (long)q_idx * L_ + tid, isf32);
    __syncthreads();
    // att[t][q] = proto[t] . query[q] + 100*qmask[q]
    for (int p = tid; p < T_ * L_; p += 256) {
        int t = p >> 7, q = p & (L_ - 1);
        const float* pp = s_proto + t * D_;
        float acc = 0.f;
        if (isf32) {
            const float4* qp = (const float4*)((const float*)qemb_raw + ((size_t)q_idx * L_ + q) * D_);
            for (int d = 0; d < D_ / 4; ++d) {
                float4 v = qp[d];
                acc += v.x * pp[4 * d] + v.y * pp[4 * d + 1] + v.z * pp[4 * d + 2] + v.w * pp[4 * d + 3];
            }
        } else {
            long base = ((long)q_idx * L_ + q) * D_;
            for (int d = 0; d < D_; ++d) acc += ldf(qemb_raw, base + d, false) * pp[d];
        }
        s_att[t][q] = acc + 100.f * s_qm[q];
    }
    __syncthreads();
    if (tid < T_) {                       // softmax over q (support path)
        int t = tid; float m = -1e30f;
        for (int q = 0; q < L_; ++q) m = fmaxf(m, s_att[t][q]);
        float ss = 0.f;
        for (int q = 0; q < L_; ++q) { float e = __expf(s_att[t][q] - m); s_ps[t][q] = e; ss += e; }
        float inv = 1.f / ss;
        for (int q = 0; q < L_; ++q) s_ps[t][q] *= inv;
    } else if (tid >= 128) {              // softmax over t (query path) -> masked weights
        int q = tid - 128; float m = -1e30f;
        float e[T_];
        #pragma unroll
        for (int t = 0; t < T_; ++t) m = fmaxf(m, s_att[t][q]);
        float ss = 0.f;
        #pragma unroll
        for (int t = 0; t < T_; ++t) { e[t] = __expf(s_att[t][q] - m); ss += e[t]; }
        float inv = s_qm[q] / ss;
        float* pp = p2m_ws + ((size_t)bq * L_ + q) * 8;
        #pragma unroll
        for (int t = 0; t < T_; ++t) pp[t] = e[t] * inv;
        pp[5] = 0.f; pp[6] = 0.f; pp[7] = 0.f;
    } else if (tid == 5) {
        float s = 0.f;
        for (int q = 0; q < L_; ++q) s += s_qm[q];
        qssum_ws[bq] = s;
    }
    __syncthreads();
    // support_[t][d] = sum_q ps[t][q] * query[q][d]   (f32 query reads)
    {
        float acc[T_][3] = {};
        for (int q = 0; q < L_; ++q) {
            long base = ((long)q_idx * L_ + q) * D_;
            float qv[3];
            #pragma unroll
            for (int s = 0; s < 3; ++s) qv[s] = ldf(qemb_raw, base + tid + s * 256, isf32);
            #pragma unroll
            for (int t = 0; t < T_; ++t) {
                float p = s_ps[t][q];
                #pragma unroll
                for (int s = 0; s < 3; ++s) acc[t][s] += p * qv[s];
            }
        }
        #pragma unroll
        for (int t = 0; t < T_; ++t)
            #pragma unroll
            for (int s = 0; s < 3; ++s)
                sup_ws[(bq * T_ + t) * D_ + tid + s * 256] = f2bf(acc[t][s]);
    }
}

// ---------------- K3: fused big GEMM (eq rows 0..127, es rows 128..132) + aggregation ----------------
__global__ __launch_bounds__(256) void k_gemm_fused(
        const u16* __restrict__ qemb, const float* __restrict__ p2m,
        const u16* __restrict__ proto_bf, const u16* __restrict__ sup_ws,
        const u16* __restrict__ projw, const float* __restrict__ projb,
        const float* __restrict__ qssum_ws, u16* __restrict__ cat_ws) {
    int bq = blockIdx.y;
    int jbase = blockIdx.x * 128;
    int q_idx = bq / N_;
    int bn = (bq / (N_ * Q_ * N_)) * N_ + (bq % N_);
    __shared__ __align__(16) u16 sA[144 * AST];
    __shared__ __align__(16) u16 sB[128 * AST];
    __shared__ __align__(16) u16 s_m2[128 * 32];       // current 32-wide slab of query_
    __shared__ __align__(16) u16 s_proto[T_ * D_];
    __shared__ __align__(16) u16 s_supf[T_ * D_];
    __shared__ float s_p2m[128 * 8];
    int tid = threadIdx.x;
    int lane = tid & 63, w = tid >> 6, quad = lane >> 4, l16 = lane & 15;

    for (int i = tid; i < 480; i += 256) {
        ((uint4*)s_proto)[i] = ((const uint4*)(proto_bf + (size_t)bn * T_ * D_))[i];
        ((uint4*)s_supf)[i]  = ((const uint4*)(sup_ws  + (size_t)bq * T_ * D_))[i];
    }
    for (int i = tid; i < 1024; i += 256) s_p2m[i] = p2m[(size_t)bq * 1024 + i];

    f32x4 zero = {0.f, 0.f, 0.f, 0.f};
    f32x4 acc[9][2];
    #pragma unroll
    for (int rt = 0; rt < 9; ++rt) { acc[rt][0] = zero; acc[rt][1] = zero; }

    for (int slab = 0; slab < 24; ++slab) {
        int d0 = slab * 32;
        for (int c = 0; c < 4; ++c) {
            int k0 = c * D_ + d0;
            __syncthreads();
            // stage A: 144 rows x 4 octets
            for (int u = tid; u < 576; u += 256) {
                int row = u >> 2, ko = (u & 3) * 8, dd = d0 + ko;
                short8 val;
                if (row < 128) {
                    if (c == 0) {
                        val = *(const short8*)(qemb + ((size_t)q_idx * L_ + row) * D_ + dd);
                    } else if (c == 1) {
                        float p0 = s_p2m[row * 8 + 0], p1 = s_p2m[row * 8 + 1];
                        float p2v = s_p2m[row * 8 + 2], p3 = s_p2m[row * 8 + 3];
                        float p4 = s_p2m[row * 8 + 4];
                        short8 r0 = *(const short8*)(s_proto + 0 * D_ + dd);
                        short8 r1 = *(const short8*)(s_proto + 1 * D_ + dd);
                        short8 r2 = *(const short8*)(s_proto + 2 * D_ + dd);
                        short8 r3 = *(const short8*)(s_proto + 3 * D_ + dd);
                        short8 r4 = *(const short8*)(s_proto + 4 * D_ + dd);
                        short8 o;
                        #pragma unroll
                        for (int i = 0; i < 8; ++i) {
                            float m2 = p0 * bf2f((u16)r0[i]) + p1 * bf2f((u16)r1[i])
                                     + p2v * bf2f((u16)r2[i]) + p3 * bf2f((u16)r3[i])
                                     + p4 * bf2f((u16)r4[i]);
                            o[i] = (short)f2bf(m2);
                        }
                        *(short8*)(s_m2 + row * 32 + ko) = o;
                        val = o;
                    } else {
                        short8 a = *(const short8*)(qemb + ((size_t)q_idx * L_ + row) * D_ + dd);
                        short8 b = *(const short8*)(s_m2 + row * 32 + ko);
                        val = fuse8(c, a, b);
                    }
                } else if (row < 133) {
                    int t = row - 128;
                    short8 a = *(const short8*)(s_proto + t * D_ + dd);
                    short8 b = *(const short8*)(s_supf + t * D_ + dd);
                    val = fuse8(c, a, b);
                } else {
                    val = short8{0, 0, 0, 0, 0, 0, 0, 0};
                }
                *(short8*)(sA + row * AST + ko) = val;
            }
            // stage B: 128 rows of proj_w
            for (int u = tid; u < 512; u += 256) {
                int row = u >> 2, ko = (u & 3) * 8;
                *(short8*)(sB + row * AST + ko) =
                    *(const short8*)(projw + (size_t)(jbase + row) * K4_ + k0 + ko);
            }
            __syncthreads();
            short8 af[9], bfr[2];
            #pragma unroll
            for (int rt = 0; rt < 9; ++rt)
                af[rt] = *(const short8*)(sA + (rt * 16 + l16) * AST + quad * 8);
            #pragma unroll
            for (int jj = 0; jj < 2; ++jj)
                bfr[jj] = *(const short8*)(sB + ((2 * w + jj) * 16 + l16) * AST + quad * 8);
            #pragma unroll
            for (int rt = 0; rt < 9; ++rt)
                #pragma unroll
                for (int jj = 0; jj < 2; ++jj)
                    acc[rt][jj] = __builtin_amdgcn_mfma_f32_16x16x32_bf16(af[rt], bfr[jj], acc[rt][jj], 0, 0, 0);
        }
    }
    // epilogue: bias + relu, reduce over rows -> cat_seq[bq][4*768]
    float inv_qs = 1.f / qssum_ws[bq];
    #pragma unroll
    for (int jj = 0; jj < 2; ++jj) {
        int col = jbase + (2 * w + jj) * 16 + l16;
        float bias = projb[col];
        float qmax = 0.f, qsum = 0.f, smax = 0.f, ssum = 0.f;
        #pragma unroll
        for (int rt = 0; rt < 8; ++rt) {       // query rows 0..127 (all valid)
            #pragma unroll
            for (int r = 0; r < 4; ++r) {
                float v = fmaxf(acc[rt][jj][r] + bias, 0.f);
                qmax = fmaxf(qmax, v); qsum += v;
            }
        }
        #pragma unroll
        for (int r = 0; r < 4; ++r) {          // support rows: t = quad*4+r, valid t<5
            int t = quad * 4 + r;
            float v = fmaxf(acc[8][jj][r] + bias, 0.f);
            if (t < T_) { smax = fmaxf(smax, v); ssum += v; }
        }
        qmax = fmaxf(qmax, __shfl_xor(qmax, 16, 64)); qmax = fmaxf(qmax, __shfl_xor(qmax, 32, 64));
        qsum += __shfl_xor(qsum, 16, 64);             qsum += __shfl_xor(qsum, 32, 64);
        smax = fmaxf(smax, __shfl_xor(smax, 16, 64)); smax = fmaxf(smax, __shfl_xor(smax, 32, 64));
        ssum += __shfl_xor(ssum, 16, 64);             ssum += __shfl_xor(ssum, 32, 64);
        if (quad == 0) {
            u16* cp = cat_ws + (size_t)bq * K4_;
            cp[col]           = f2bf(qmax);
            cp[D_ + col]      = f2bf(qsum * inv_qs);
            cp[2 * D_ + col]  = f2bf(smax);
            cp[3 * D_ + col]  = f2bf(ssum * 0.2f);
        }
    }
}

// ---------------- K5: relation MLP GEMM: h = relu(cat @ rel_w1^T + b1) ----------------
__global__ __launch_bounds__(256) void k_relmlp(const u16* __restrict__ cat_ws,
                                                const u16* __restrict__ w1, const float* __restrict__ b1,
                                                u16* __restrict__ h_ws) {
    int mbase = blockIdx.y * 64;
    int jbase = blockIdx.x * 128;
    __shared__ __align__(16) u16 sA[64 * AST];
    __shared__ __align__(16) u16 sB[128 * AST];
    int tid = threadIdx.x;
    int lane = tid & 63, w = tid >> 6, quad = lane >> 4, l16 = lane & 15;
    f32x4 zero = {0.f, 0.f, 0.f, 0.f};
    f32x4 acc[4][2];
    #pragma unroll
    for (int rt = 0; rt < 4; ++rt) { acc[rt][0] = zero; acc[rt][1] = zero; }

    for (int kt = 0; kt < K4_ / 32; ++kt) {
        int k0 = kt * 32;
        __syncthreads();
        {   // stage A: 64 rows x 4 octets = 256 units
            int row = tid >> 2, ko = (tid & 3) * 8;
            int grow = mbase + row;
            short8 val = short8{0, 0, 0, 0, 0, 0, 0, 0};
            if (grow < BQ_) val = *(const short8*)(cat_ws + (size_t)grow * K4_ + k0 + ko);
            *(short8*)(sA + row * AST + ko) = val;
        }
        for (int u = tid; u < 512; u += 256) {
            int row = u >> 2, ko = (u & 3) * 8;
            *(short8*)(sB + row * AST + ko) =
                *(const short8*)(w1 + (size_t)(jbase + row) * K4_ + k0 + ko);
        }
        __syncthreads();
        short8 af[4], bfr[2];
        #pragma unroll
        for (int rt = 0; rt < 4; ++rt)
            af[rt] = *(const short8*)(sA + (rt * 16 + l16) * AST + quad * 8);
        #pragma unroll
        for (int jj = 0; jj < 2; ++jj)
            bfr[jj] = *(const short8*)(sB + ((2 * w + jj) * 16 + l16) * AST + quad * 8);
        #pragma unroll
        for (int rt = 0; rt < 4; ++rt)
            #pragma unroll
            for (int jj = 0; jj < 2; ++jj)
                acc[rt][jj] = __builtin_amdgcn_mfma_f32_16x16x32_bf16(af[rt], bfr[jj], acc[rt][jj], 0, 0, 0);
    }
    #pragma unroll
    for (int jj = 0; jj < 2; ++jj) {
        int col = jbase + (2 * w + jj) * 16 + l16;
        float bias = b1[col];
        #pragma unroll
        for (int rt = 0; rt < 4; ++rt) {
            #pragma unroll
            for (int r = 0; r < 4; ++r) {
                int grow = mbase + rt * 16 + quad * 4 + r;
                float v = fmaxf(acc[rt][jj][r] + bias, 0.f);
                if (grow < BQ_) h_ws[(size_t)grow * D_ + col] = f2bf(v);
            }
        }
    }
}

// ---------------- K6: logits = h . rel_w2 + b2  (f32 output!) ----------------
__global__ void k_logits(const u16* __restrict__ h_ws, const float* __restrict__ w2,
                         const float* __restrict__ b2, float* __restrict__ out) {
    int wv = threadIdx.x >> 6, lane = threadIdx.x & 63;
    int bq = blockIdx.x * 4 + wv;
    float acc = 0.f;
    for (int d = lane; d < D_; d += 64) acc += bf2f(h_ws[(size_t)bq * D_ + d]) * w2[d];
    #pragma unroll
    for (int m = 32; m >= 1; m >>= 1) acc += __shfl_down(acc, m, 64);
    if (lane == 0) out[bq] = acc + b2[0];
}

extern "C" void kernel_launch(void* const* d_in, const int* in_sizes, int n_in,
                              void* d_out, int out_size, void* d_ws, size_t ws_size,
                              hipStream_t stream) {
    (void)in_sizes; (void)n_in; (void)out_size; (void)ws_size;
    const void* semb  = d_in[0];
    const void* qemb  = d_in[1];
    const void* smask = d_in[2];
    const void* qmask = d_in[3];
    const void* label = d_in[4];
    const void* projw = d_in[5];
    const float* projb = (const float*)d_in[6];
    const void* relw1 = d_in[7];
    const float* relb1 = (const float*)d_in[8];
    const float* relw2 = (const float*)d_in[9];
    const float* relb2 = (const float*)d_in[10];
    const u16* det = (const u16*)smask;

    char* ws = (char*)d_ws;
    u16*   qemb_bf   = (u16*)  (ws + 0);           // 7,864,320
    u16*   projw_bf  = (u16*)  (ws + 7864320);     // 4,718,592
    u16*   relw1_bf  = (u16*)  (ws + 12582912);    // 4,718,592
    float* proto_shot= (float*)(ws + 17301504);    // 768,000
    float* proto_f32 = (float*)(ws + 18069504);    // 153,600
    u16*   proto_bf  = (u16*)  (ws + 18223104);    // 76,800
    u16*   sup_ws    = (u16*)  (ws + 18299904);    // 1,536,000
    float* p2m_ws    = (float*)(ws + 19835904);    // 819,200
    float* qssum     = (float*)(ws + 20655104);    // 800
    u16*   cat_ws    = (u16*)  (ws + 20655904);    // 1,228,800
    u16*   h_ws      = (u16*)  (ws + 21884704);    // 307,200
    // total ~22.2 MB

    k_convert<<<2048, 256, 0, stream>>>(qemb,  qemb_bf,  QEMB_N,  det);
    k_convert<<<1024, 256, 0, stream>>>(projw, projw_bf, PROJW_N, det);
    k_convert<<<1024, 256, 0, stream>>>(relw1, relw1_bf, PROJW_N, det);

    k_proto_shot<<<BNK_, 256, 0, stream>>>(label, smask, semb, proto_shot);
    k_proto_mean<<<150, 256, 0, stream>>>(proto_shot, proto_f32, proto_bf);
    k_attn<<<BQ_, 256, 0, stream>>>(qemb, qmask, proto_f32, sup_ws, p2m_ws, qssum);
    k_gemm_fused<<<dim3(6, BQ_), 256, 0, stream>>>(qemb_bf, p2m_ws, proto_bf, sup_ws,
                                                   projw_bf, projb, qssum, cat_ws);
    k_relmlp<<<dim3(6, 4), 256, 0, stream>>>(cat_ws, relw1_bf, relb1, h_ws);
    k_logits<<<50, 256, 0, stream>>>(h_ws, relw2, relb2, (float*)d_out);
}

// Round 5
// 680.123 us; speedup vs baseline: 1.0644x; 1.0644x over previous
//
#include <hip/hip_runtime.h>

typedef unsigned short u16;
typedef __attribute__((ext_vector_type(8))) short short8;
typedef __attribute__((ext_vector_type(4))) float f32x4;

#define B_   2
#define N_   5
#define K_   5
#define Q_   4
#define T_   5
#define D_   768
#define L_   128
#define BN_  (B_*N_)            // 10
#define BNK_ (B_*N_*K_)         // 50
#define BQ_  (B_*N_*Q_*N_)      // 200
#define K4_  (4*D_)             // 3072

#define QEMB_N  (40*128*768)    // 3,932,160
#define PROJW_N (768*3072)      // 2,359,296

__device__ __forceinline__ float bf2f(u16 u) {
    return __uint_as_float(((unsigned)u) << 16);
}
__device__ __forceinline__ u16 f2bf(float f) {
    unsigned u = __float_as_uint(f);
    return (u16)((u + 0x7fffu + ((u >> 16) & 1u)) >> 16);
}

// ---------------- K0: convert qemb/projw/relw1 f32 -> bf16 (one fused kernel) ----------------
__global__ void k_convert3(const float* __restrict__ q, const float* __restrict__ pw,
                           const float* __restrict__ rw, u16* __restrict__ qo,
                           u16* __restrict__ po, u16* __restrict__ ro) {
    const long n1 = QEMB_N / 4, n2 = PROJW_N / 4;
    const long total = n1 + 2 * n2;
    for (long i = (long)blockIdx.x * 256 + threadIdx.x; i < total; i += (long)gridDim.x * 256) {
        const float* src; u16* dst; long k;
        if (i < n1)            { src = q;  dst = qo; k = i; }
        else if (i < n1 + n2)  { src = pw; dst = po; k = i - n1; }
        else                   { src = rw; dst = ro; k = i - n1 - n2; }
        float4 v = ((const float4*)src)[k];
        u16 o[4] = {f2bf(v.x), f2bf(v.y), f2bf(v.z), f2bf(v.w)};
        *(uint2*)(dst + k * 4) = *(const uint2*)o;
    }
}

// ---------------- K1: per-shot tag prototypes ----------------
__global__ void k_proto_shot(const float* __restrict__ label, const float* __restrict__ smask,
                             const float* __restrict__ semb, float* __restrict__ proto_shot) {
    int bnk = blockIdx.x;
    __shared__ int   s_tag[L_];
    __shared__ float s_w[L_];
    __shared__ float s_cnt[T_];
    int tid = threadIdx.x;
    if (tid < L_) {
        const float* lp = label + ((long)bnk * L_ + tid) * T_;
        float best = lp[0]; int bi = 0;
        #pragma unroll
        for (int t = 1; t < T_; ++t) { float v = lp[t]; if (v > best) { best = v; bi = t; } }
        s_tag[tid] = bi;
        s_w[tid]   = (bi == 0) ? smask[(long)bnk * L_ + tid] : 1.0f;  // tag 'O' gated by mask
    }
    __syncthreads();
    if (tid < T_) {
        float c = 0.f;
        for (int l = 0; l < L_; ++l) if (s_tag[l] == tid) c += s_w[l];
        s_cnt[tid] = c;
    }
    __syncthreads();
    float acc[3][T_] = {};
    for (int l = 0; l < L_; ++l) {
        float w = s_w[l]; int tg = s_tag[l];
        const float* ep = semb + ((long)bnk * L_ + l) * D_;
        #pragma unroll
        for (int s = 0; s < 3; ++s) {
            float e = ep[tid + s * 256] * w;
            #pragma unroll
            for (int t = 0; t < T_; ++t) acc[s][t] += (tg == t) ? e : 0.0f;
        }
    }
    #pragma unroll
    for (int s = 0; s < 3; ++s) {
        int d = tid + s * 256;
        #pragma unroll
        for (int t = 0; t < T_; ++t) {
            float c = s_cnt[t];
            float v = (c > 0.f) ? acc[s][t] / fmaxf(c, 1.f) : 0.f;
            proto_shot[(bnk * T_ + t) * D_ + d] = v;
        }
    }
}

// ---------------- K1b: mean over K shots ----------------
__global__ void k_proto_mean(const float* __restrict__ proto_shot,
                             float* __restrict__ proto_f32, u16* __restrict__ proto_bf) {
    int idx = blockIdx.x * 256 + threadIdx.x;              // < 10*5*768 = 38400
    if (idx >= BN_ * T_ * D_) return;
    int bn = idx / (T_ * D_);
    int rem = idx - bn * (T_ * D_);
    float s = 0.f;
    #pragma unroll
    for (int k = 0; k < K_; ++k) s += proto_shot[(bn * K_ + k) * (T_ * D_) + rem];
    s *= (1.f / K_);
    proto_f32[idx] = s;
    proto_bf[idx]  = f2bf(s);
}

// ---------------- K2: co-attention -> es-fuse rows (bf16), p2m weights, qssum ----------------
__global__ void k_attn(const float* __restrict__ qemb, const float* __restrict__ qmask_g,
                       const float* __restrict__ proto_f32,
                       u16* __restrict__ esf, float* __restrict__ p2m_ws,
                       float* __restrict__ qssum_ws) {
    int bq = blockIdx.x;
    int q_idx = bq / N_;
    int bn = (bq / (N_ * Q_ * N_)) * N_ + (bq % N_);
    __shared__ float s_proto[T_ * D_];
    __shared__ float s_att[T_][L_];
    __shared__ float s_ps[T_][L_];
    __shared__ float s_qm[L_];
    int tid = threadIdx.x;
    for (int i = tid; i < T_ * D_; i += 256) s_proto[i] = proto_f32[bn * T_ * D_ + i];
    if (tid < L_) s_qm[tid] = qmask_g[(long)q_idx * L_ + tid];
    __syncthreads();
    // att[t][q] = proto[t] . query[q] + 100*qmask[q]
    for (int p = tid; p < T_ * L_; p += 256) {
        int t = p >> 7, q = p & (L_ - 1);
        const float* pp = s_proto + t * D_;
        const float4* qp = (const float4*)(qemb + ((size_t)q_idx * L_ + q) * D_);
        float acc = 0.f;
        for (int d = 0; d < D_ / 4; ++d) {
            float4 v = qp[d];
            acc += v.x * pp[4 * d] + v.y * pp[4 * d + 1] + v.z * pp[4 * d + 2] + v.w * pp[4 * d + 3];
        }
        s_att[t][q] = acc + 100.f * s_qm[q];
    }
    __syncthreads();
    if (tid < T_) {                       // softmax over q (support path)
        int t = tid; float m = -1e30f;
        for (int q = 0; q < L_; ++q) m = fmaxf(m, s_att[t][q]);
        float ss = 0.f;
        for (int q = 0; q < L_; ++q) { float e = __expf(s_att[t][q] - m); s_ps[t][q] = e; ss += e; }
        float inv = 1.f / ss;
        for (int q = 0; q < L_; ++q) s_ps[t][q] *= inv;
    } else if (tid >= 128) {              // softmax over t (query path) -> masked weights
        int q = tid - 128; float m = -1e30f;
        float e[T_];
        #pragma unroll
        for (int t = 0; t < T_; ++t) m = fmaxf(m, s_att[t][q]);
        float ss = 0.f;
        #pragma unroll
        for (int t = 0; t < T_; ++t) { e[t] = __expf(s_att[t][q] - m); ss += e[t]; }
        float inv = s_qm[q] / ss;
        #pragma unroll
        for (int t = 0; t < T_; ++t) p2m_ws[((size_t)bq * T_ + t) * L_ + q] = e[t] * inv;
    } else if (tid == 5) {
        float s = 0.f;
        for (int q = 0; q < L_; ++q) s += s_qm[q];
        qssum_ws[bq] = s;
    }
    __syncthreads();
    // support_[t][d] = sum_q ps[t][q] * query[q][d]; then write all 4 fuse chunks (f32 math)
    {
        float acc[T_][3] = {};
        for (int q = 0; q < L_; ++q) {
            const float* qp = qemb + ((size_t)q_idx * L_ + q) * D_;
            float qv[3];
            #pragma unroll
            for (int s = 0; s < 3; ++s) qv[s] = qp[tid + s * 256];
            #pragma unroll
            for (int t = 0; t < T_; ++t) {
                float p = s_ps[t][q];
                #pragma unroll
                for (int s = 0; s < 3; ++s) acc[t][s] += p * qv[s];
            }
        }
        #pragma unroll
        for (int t = 0; t < T_; ++t) {
            #pragma unroll
            for (int s = 0; s < 3; ++s) {
                int d = tid + s * 256;
                float p = s_proto[t * D_ + d];
                float sv = acc[t][s];
                size_t base = (((size_t)bq * T_ + t) * 4) * (size_t)D_ + d;
                esf[base]            = f2bf(p);
                esf[base + D_]       = f2bf(sv);
                esf[base + 2 * D_]   = f2bf(fabsf(p - sv));
                esf[base + 3 * D_]   = f2bf(p * sv);
            }
        }
    }
}

// ---------------- K3: fused big GEMM (144 x 256 per block) + aggregation ----------------
// grid (3 jchunks of 256 cols, 200 bq), block 256 (4 waves). Fragment-order LDS,
// register-prefetch pipeline: next tile's global loads issue during MFMA.
__global__ __launch_bounds__(256) void k_gemm_fused(
        const u16* __restrict__ qemb, const float* __restrict__ p2m,
        const u16* __restrict__ proto_bf, const u16* __restrict__ esf,
        const u16* __restrict__ projw, const float* __restrict__ projb,
        const float* __restrict__ qssum_ws, u16* __restrict__ cat_ws) {
    int bq = blockIdx.y;
    int jbase = blockIdx.x * 256;
    int q_idx = bq / N_;
    int bn = (bq / (N_ * Q_ * N_)) * N_ + (bq % N_);
    __shared__ __align__(16) u16 sA[9 * 4 * 128];    // [rt][quad][l16*8] fragment order
    __shared__ __align__(16) u16 sB[16 * 4 * 128];   // [ct][quad][l16*8]
    __shared__ __align__(16) u16 s_q[128 * 32];      // qemb slab (plain)
    __shared__ __align__(16) u16 s_m2[128 * 32];     // query_ slab (plain)
    __shared__ __align__(16) u16 s_ps[8 * 32];       // proto slab (5 rows used)
    __shared__ float s_p2m[T_ * 128];
    int tid = threadIdx.x;
    int lane = tid & 63, w = tid >> 6, quad = lane >> 4, l16 = lane & 15;

    for (int i = tid; i < 640; i += 256) s_p2m[i] = p2m[(size_t)bq * 640 + i];
    // zero the pad rows 133..143 (rt=8 region), never rewritten for l16>=5
    if (tid < 128) *(uint4*)(sA + 8 * 4 * 128 + tid * 8) = uint4{0u, 0u, 0u, 0u};

    f32x4 zero = {0.f, 0.f, 0.f, 0.f};
    f32x4 acc[9][4];
    #pragma unroll
    for (int rt = 0; rt < 9; ++rt)
        #pragma unroll
        for (int jj = 0; jj < 4; ++jj) acc[rt][jj] = zero;

    // ---- initial prefetch for it=0 (slab 0, c 0) ----
    uint4 bpre[4], qpre[2], epre, ppre;
    {
        #pragma unroll
        for (int j = 0; j < 4; ++j) {
            int v = tid + j * 256, row = v >> 2, ko = v & 3;
            bpre[j] = *(const uint4*)(projw + (size_t)(jbase + row) * K4_ + ko * 8);
        }
        #pragma unroll
        for (int j = 0; j < 2; ++j) {
            int row = (tid >> 2) + j * 64, ko = tid & 3;
            qpre[j] = *(const uint4*)(qemb + ((size_t)q_idx * L_ + row) * D_ + ko * 8);
        }
        if (tid < 20) {
            int t = tid >> 2, ko = tid & 3;
            epre = *(const uint4*)(esf + (((size_t)bq * T_ + t) * 4) * (size_t)D_ + ko * 8);
        }
        if (tid >= 20 && tid < 40) {
            int i = tid - 20, t = i >> 2, ko = i & 3;
            ppre = *(const uint4*)(proto_bf + ((size_t)bn * T_ + t) * D_ + ko * 8);
        }
    }

    for (int it = 0; it < 96; ++it) {
        int c = it & 3, d0 = (it >> 2) * 32;
        (void)d0;
        __syncthreads();
        // ---- stage B from regs (frag order) ----
        #pragma unroll
        for (int j = 0; j < 4; ++j) {
            int v = tid + j * 256, row = v >> 2, ko = v & 3;
            *(uint4*)(sB + (((row >> 4) * 4 + ko) * 16 + (row & 15)) * 8) = bpre[j];
        }
        // ---- stage A rows 0..127 ----
        #pragma unroll
        for (int j = 0; j < 2; ++j) {
            int u = tid + j * 256, row = u >> 2, ko = u & 3;
            short8 val;
            if (c == 0) {
                val = *(const short8*)&qpre[j];
                *(short8*)(s_q + row * 32 + ko * 8) = val;
            } else if (c == 1) {
                float p0 = s_p2m[row], p1 = s_p2m[128 + row], p2v = s_p2m[256 + row];
                float p3 = s_p2m[384 + row], p4 = s_p2m[512 + row];
                short8 r0 = *(const short8*)(s_ps + 0 * 32 + ko * 8);
                short8 r1 = *(const short8*)(s_ps + 1 * 32 + ko * 8);
                short8 r2 = *(const short8*)(s_ps + 2 * 32 + ko * 8);
                short8 r3 = *(const short8*)(s_ps + 3 * 32 + ko * 8);
                short8 r4 = *(const short8*)(s_ps + 4 * 32 + ko * 8);
                short8 o;
                #pragma unroll
                for (int i = 0; i < 8; ++i) {
                    float m2 = p0 * bf2f((u16)r0[i]) + p1 * bf2f((u16)r1[i])
                             + p2v * bf2f((u16)r2[i]) + p3 * bf2f((u16)r3[i])
                             + p4 * bf2f((u16)r4[i]);
                    o[i] = (short)f2bf(m2);
                }
                *(short8*)(s_m2 + row * 32 + ko * 8) = o;
                val = o;
            } else {
                short8 a = *(const short8*)(s_q + row * 32 + ko * 8);
                short8 b = *(const short8*)(s_m2 + row * 32 + ko * 8);
                short8 o;
                #pragma unroll
                for (int i = 0; i < 8; ++i) {
                    float x = bf2f((u16)a[i]), y = bf2f((u16)b[i]);
                    float r = (c == 2) ? fabsf(x - y) : x * y;
                    o[i] = (short)f2bf(r);
                }
                val = o;
            }
            *(short8*)(sA + (((row >> 4) * 4 + ko) * 16 + (row & 15)) * 8) = val;
        }
        // ---- stage A rows 128..132 (es-fuse, precomputed) ----
        if (tid < 20) {
            int t = tid >> 2, ko = tid & 3;
            *(uint4*)(sA + ((8 * 4 + ko) * 16 + t) * 8) = epre;
        }
        // ---- proto slab for the upcoming c==1 phase ----
        if (c == 0 && tid >= 20 && tid < 40) {
            int i = tid - 20, t = i >> 2, ko = i & 3;
            *(uint4*)(s_ps + t * 32 + ko * 8) = ppre;
        }
        __syncthreads();
        // ---- prefetch next tile (latency overlaps MFMA) ----
        int nit = it + 1;
        if (nit < 96) {
            int ns = nit >> 2, nc = nit & 3;
            int nk0 = nc * D_ + ns * 32;
            #pragma unroll
            for (int j = 0; j < 4; ++j) {
                int v = tid + j * 256, row = v >> 2, ko = v & 3;
                bpre[j] = *(const uint4*)(projw + (size_t)(jbase + row) * K4_ + nk0 + ko * 8);
            }
            if (tid < 20) {
                int t = tid >> 2, ko = tid & 3;
                epre = *(const uint4*)(esf + (((size_t)bq * T_ + t) * 4 + nc) * (size_t)D_ + ns * 32 + ko * 8);
            }
            if (nc == 0) {
                #pragma unroll
                for (int j = 0; j < 2; ++j) {
                    int row = (tid >> 2) + j * 64, ko = tid & 3;
                    qpre[j] = *(const uint4*)(qemb + ((size_t)q_idx * L_ + row) * D_ + ns * 32 + ko * 8);
                }
                if (tid >= 20 && tid < 40) {
                    int i = tid - 20, t = i >> 2, ko = i & 3;
                    ppre = *(const uint4*)(proto_bf + ((size_t)bn * T_ + t) * D_ + ns * 32 + ko * 8);
                }
            }
        }
        // ---- fragments + MFMA ----
        short8 af[9], bfr[4];
        #pragma unroll
        for (int rt = 0; rt < 9; ++rt)
            af[rt] = *(const short8*)(sA + ((rt * 4 + quad) * 16 + l16) * 8);
        #pragma unroll
        for (int jj = 0; jj < 4; ++jj)
            bfr[jj] = *(const short8*)(sB + (((w * 4 + jj) * 4 + quad) * 16 + l16) * 8);
        #pragma unroll
        for (int rt = 0; rt < 9; ++rt)
            #pragma unroll
            for (int jj = 0; jj < 4; ++jj)
                acc[rt][jj] = __builtin_amdgcn_mfma_f32_16x16x32_bf16(af[rt], bfr[jj], acc[rt][jj], 0, 0, 0);
    }
    // ---- epilogue: bias + relu, reduce over rows -> cat_seq[bq][4*768] ----
    float inv_qs = 1.f / qssum_ws[bq];
    #pragma unroll
    for (int jj = 0; jj < 4; ++jj) {
        int col = jbase + (w * 4 + jj) * 16 + l16;
        float bias = projb[col];
        float qmax = 0.f, qsum = 0.f, smax = 0.f, ssum = 0.f;
        #pragma unroll
        for (int rt = 0; rt < 8; ++rt) {       // query rows 0..127
            #pragma unroll
            for (int r = 0; r < 4; ++r) {
                float v = fmaxf(acc[rt][jj][r] + bias, 0.f);
                qmax = fmaxf(qmax, v); qsum += v;
            }
        }
        #pragma unroll
        for (int r = 0; r < 4; ++r) {          // support rows: t = quad*4+r, valid t<5
            int t = quad * 4 + r;
            float v = fmaxf(acc[8][jj][r] + bias, 0.f);
            if (t < T_) { smax = fmaxf(smax, v); ssum += v; }
        }
        qmax = fmaxf(qmax, __shfl_xor(qmax, 16, 64)); qmax = fmaxf(qmax, __shfl_xor(qmax, 32, 64));
        qsum += __shfl_xor(qsum, 16, 64);             qsum += __shfl_xor(qsum, 32, 64);
        smax = fmaxf(smax, __shfl_xor(smax, 16, 64)); smax = fmaxf(smax, __shfl_xor(smax, 32, 64));
        ssum += __shfl_xor(ssum, 16, 64);             ssum += __shfl_xor(ssum, 32, 64);
        if (quad == 0) {
            u16* cp = cat_ws + (size_t)bq * K4_;
            cp[col]           = f2bf(qmax);
            cp[D_ + col]      = f2bf(qsum * inv_qs);
            cp[2 * D_ + col]  = f2bf(smax);
            cp[3 * D_ + col]  = f2bf(ssum * 0.2f);
        }
    }
}

// ---------------- K5: relation MLP GEMM, split-K -> f32 partials ----------------
// grid (6 jchunks, 4 mchunks of 64, 8 ksplits), block 256
#define AST  40
__global__ __launch_bounds__(256) void k_relmlp(const u16* __restrict__ cat_ws,
                                                const u16* __restrict__ w1,
                                                float* __restrict__ part) {
    int mbase = blockIdx.y * 64;
    int jbase = blockIdx.x * 128;
    int ks = blockIdx.z;
    __shared__ __align__(16) u16 sA[64 * AST];
    __shared__ __align__(16) u16 sB[128 * AST];
    int tid = threadIdx.x;
    int lane = tid & 63, w = tid >> 6, quad = lane >> 4, l16 = lane & 15;
    f32x4 zero = {0.f, 0.f, 0.f, 0.f};
    f32x4 acc[4][2];
    #pragma unroll
    for (int rt = 0; rt < 4; ++rt) { acc[rt][0] = zero; acc[rt][1] = zero; }

    for (int kt = ks * 12; kt < ks * 12 + 12; ++kt) {
        int k0 = kt * 32;
        __syncthreads();
        {
            int row = tid >> 2, ko = (tid & 3) * 8;
            int grow = mbase + row;
            short8 val = short8{0, 0, 0, 0, 0, 0, 0, 0};
            if (grow < BQ_) val = *(const short8*)(cat_ws + (size_t)grow * K4_ + k0 + ko);
            *(short8*)(sA + row * AST + ko) = val;
        }
        for (int u = tid; u < 512; u += 256) {
            int row = u >> 2, ko = (u & 3) * 8;
            *(short8*)(sB + row * AST + ko) =
                *(const short8*)(w1 + (size_t)(jbase + row) * K4_ + k0 + ko);
        }
        __syncthreads();
        short8 af[4], bfr[2];
        #pragma unroll
        for (int rt = 0; rt < 4; ++rt)
            af[rt] = *(const short8*)(sA + (rt * 16 + l16) * AST + quad * 8);
        #pragma unroll
        for (int jj = 0; jj < 2; ++jj)
            bfr[jj] = *(const short8*)(sB + ((2 * w + jj) * 16 + l16) * AST + quad * 8);
        #pragma unroll
        for (int rt = 0; rt < 4; ++rt)
            #pragma unroll
            for (int jj = 0; jj < 2; ++jj)
                acc[rt][jj] = __builtin_amdgcn_mfma_f32_16x16x32_bf16(af[rt], bfr[jj], acc[rt][jj], 0, 0, 0);
    }
    #pragma unroll
    for (int jj = 0; jj < 2; ++jj) {
        int col = jbase + (2 * w + jj) * 16 + l16;
        #pragma unroll
        for (int rt = 0; rt < 4; ++rt) {
            #pragma unroll
            for (int r = 0; r < 4; ++r) {
                int grow = mbase + rt * 16 + quad * 4 + r;
                if (grow < BQ_)
                    part[((size_t)ks * BQ_ + grow) * D_ + col] = acc[rt][jj][r];
            }
        }
    }
}

// ---------------- K6: finish — sum partials, bias+relu, dot w2 (all f32) ----------------
__global__ void k_rel_fin(const float* __restrict__ part, const float* __restrict__ b1,
                          const float* __restrict__ w2, const float* __restrict__ b2,
                          float* __restrict__ out) {
    int bq = blockIdx.x, tid = threadIdx.x;
    float a = 0.f;
    #pragma unroll
    for (int s = 0; s < 3; ++s) {
        int col = tid + s * 256;
        float sum = 0.f;
        #pragma unroll
        for (int ks = 0; ks < 8; ++ks) sum += part[((size_t)ks * BQ_ + bq) * D_ + col];
        float h = fmaxf(sum + b1[col], 0.f);
        a += h * w2[col];
    }
    __shared__ float red[256];
    red[tid] = a; __syncthreads();
    for (int off = 128; off >= 1; off >>= 1) {
        if (tid < off) red[tid] += red[tid + off];
        __syncthreads();
    }
    if (tid == 0) out[bq] = red[0] + b2[0];
}

extern "C" void kernel_launch(void* const* d_in, const int* in_sizes, int n_in,
                              void* d_out, int out_size, void* d_ws, size_t ws_size,
                              hipStream_t stream) {
    (void)in_sizes; (void)n_in; (void)out_size; (void)ws_size;
    const float* semb  = (const float*)d_in[0];
    const float* qemb  = (const float*)d_in[1];
    const float* smask = (const float*)d_in[2];
    const float* qmask = (const float*)d_in[3];
    const float* label = (const float*)d_in[4];
    const float* projw = (const float*)d_in[5];
    const float* projb = (const float*)d_in[6];
    const float* relw1 = (const float*)d_in[7];
    const float* relb1 = (const float*)d_in[8];
    const float* relw2 = (const float*)d_in[9];
    const float* relb2 = (const float*)d_in[10];

    char* ws = (char*)d_ws;
    u16*   qemb_bf   = (u16*)  (ws + 0);           // 7,864,320
    u16*   projw_bf  = (u16*)  (ws + 7864320);     // 4,718,592
    u16*   relw1_bf  = (u16*)  (ws + 12582912);    // 4,718,592
    float* proto_shot= (float*)(ws + 17301504);    // 768,000
    float* proto_f32 = (float*)(ws + 18069504);    // 153,600
    u16*   proto_bf  = (u16*)  (ws + 18223104);    // 76,800
    u16*   esf_ws    = (u16*)  (ws + 18299904);    // 200*5*4*768*2 = 6,144,000
    float* p2m_ws    = (float*)(ws + 24443904);    // 200*5*128*4   = 512,000
    float* qssum     = (float*)(ws + 24955904);    // 800
    u16*   cat_ws    = (u16*)  (ws + 24956704);    // 1,228,800
    float* part_ws   = (float*)(ws + 26185504);    // 8*200*768*4   = 4,915,200
    // total 31,100,704 bytes (~31.1 MB)

    k_convert3<<<2048, 256, 0, stream>>>(qemb, projw, relw1, qemb_bf, projw_bf, relw1_bf);
    k_proto_shot<<<BNK_, 256, 0, stream>>>(label, smask, semb, proto_shot);
    k_proto_mean<<<150, 256, 0, stream>>>(proto_shot, proto_f32, proto_bf);
    k_attn<<<BQ_, 256, 0, stream>>>(qemb, qmask, proto_f32, esf_ws, p2m_ws, qssum);
    k_gemm_fused<<<dim3(3, BQ_), 256, 0, stream>>>(qemb_bf, p2m_ws, proto_bf, esf_ws,
                                                   projw_bf, projb, qssum, cat_ws);
    k_relmlp<<<dim3(6, 4, 8), 256, 0, stream>>>(cat_ws, relw1_bf, part_ws);
    k_rel_fin<<<BQ_, 256, 0, stream>>>(part_ws, relb1, relw2, relb2, (float*)d_out);
}